// Round 2
// baseline (204.887 us; speedup 1.0000x reference)
//
#include <hip/hip_runtime.h>
#include <math.h>

#define SCALE 0.1020620726159658f  // 96^-0.5

typedef __attribute__((ext_vector_type(8))) short shortx8;
typedef __attribute__((ext_vector_type(4))) float floatx4;

__device__ __forceinline__ float bf2f(unsigned short u) {
  union { unsigned int i; float f; } c; c.i = ((unsigned int)u) << 16; return c.f;
}
__device__ __forceinline__ unsigned short f2bf(float f) {
  union { float f; unsigned int i; } c; c.f = f;
  unsigned int x = c.i;
  x += 0x7fffu + ((x >> 16) & 1u);
  return (unsigned short)(x >> 16);
}
__device__ __forceinline__ float geluf(float x) {
  return 0.5f * x * (1.0f + erff(x * 0.70710678118654752f));
}
// flag-aware element load: fp32 world reads float, bf16 world reads ushort
__device__ __forceinline__ float lde(const void* p, long i, int fp32) {
  return fp32 ? ((const float*)p)[i] : bf2f(((const unsigned short*)p)[i]);
}

// Detect input dtype from `search` (N(0,1) data). fp32-world: low shorts of
// floats have uniform-random bf16 exponent fields -> some >= 160 among 256
// shorts w.p. 1-e^-60. bf16-world: |x|<~10 -> exponent <= ~130. flag=1 => fp32.
__global__ void detect_dtype(const unsigned short* __restrict__ s, int* __restrict__ flag) {
  int t = threadIdx.x;
  int big = 0;
  for (int i = t; i < 256; i += 64) {
    int e = (s[i] >> 7) & 0xFF;
    if (e >= 160) big = 1;
  }
  unsigned long long m = __ballot(big);
  if (t == 0) *flag = (m != 0ULL) ? 1 : 0;
}

// query (196608) and Wq (589824) -> canonical bf16 copies in ws
__global__ void convert_in(const void* __restrict__ q, const void* __restrict__ wq,
                           unsigned short* __restrict__ qb, unsigned short* __restrict__ wqb,
                           const int* __restrict__ flagp) {
  int fl = *flagp;
  int idx = blockIdx.x * 256 + threadIdx.x;
  const int n1 = 196608;
  if (idx < n1) {
    qb[idx] = fl ? f2bf(((const float*)q)[idx]) : ((const unsigned short*)q)[idx];
  } else {
    int j = idx - n1;  // < 589824 by grid size
    wqb[j] = fl ? f2bf(((const float*)wq)[j]) : ((const unsigned short*)wq)[j];
  }
}

// WkT[d][e] = Wk[e][d], 768x768, output bf16 (input per flag)
__global__ void transpose_bf(const void* __restrict__ in, unsigned short* __restrict__ out,
                             const int* __restrict__ flagp) {
  int fl = *flagp;
  __shared__ unsigned short tile[32][33];
  int tx = threadIdx.x, ty = threadIdx.y;
#pragma unroll
  for (int i = 0; i < 4; i++)
    tile[ty + i * 8][tx] =
        f2bf(lde(in, (long)(blockIdx.y * 32 + ty + i * 8) * 768 + blockIdx.x * 32 + tx, fl));
  __syncthreads();
  int ox = blockIdx.y * 32 + tx;
#pragma unroll
  for (int i = 0; i < 4; i++)
    out[(long)(blockIdx.x * 32 + ty + i * 8) * 768 + ox] = tile[tx][ty + i * 8];
}

// C = A @ B^T. A: MxK bf16 row-major (always bf16, from ws). B: NxK row-major,
// bf16 unless (useflag && *flagp) -> fp32 converted during staging.
// 128x128 tile, BK=64, 256 threads / 4 waves, vector-load + ds_write staging,
// XOR chunk swizzle (2-way LDS aliasing max = free).
// EPI 0: fp32 store + flag-dtype column-bias  (q projection)
// EPI 1: bf16 store                            (QQ)
// EPI 2: fused MLP epilogue; rows are b*4+j; out[b,n] =
//        b2 + sum_j W2[j]*gelu(C[b*4+j,n]+cp[b*4+j]); store dtype per flag
template <int EPI>
__global__ __launch_bounds__(256) void gemm_bt(
    const unsigned short* __restrict__ A,
    const void* __restrict__ B,
    void* __restrict__ Cout,
    const void* __restrict__ biasp,   // EPI0: bq (flag dtype); EPI2: cp (float)
    const void* __restrict__ W2b,     // EPI2: W2 (flag dtype)
    const void* __restrict__ b2b,     // EPI2: b2 (flag dtype)
    const int* __restrict__ flagp, int useflag,
    int M, int N, int K)
{
  __shared__ unsigned short As[128 * 64];
  __shared__ unsigned short Bs[128 * 64];
  const int fl = *flagp;
  const int bfp32 = useflag ? fl : 0;
  const int tid = threadIdx.x;
  const int wave = tid >> 6;
  const int lane = tid & 63;
  const int wr = wave >> 1, wc = wave & 1;
  const int m0 = blockIdx.y * 128;
  const int n0 = blockIdx.x * 128;

  floatx4 acc[4][4];
#pragma unroll
  for (int i = 0; i < 4; i++)
#pragma unroll
    for (int j = 0; j < 4; j++) acc[i][j] = (floatx4){0.f, 0.f, 0.f, 0.f};

  const int cL = lane & 7;        // logical k-chunk this lane stages
  const int quad = lane >> 4;
  const int l15 = lane & 15;

  for (int k0 = 0; k0 < K; k0 += 64) {
    // ---- stage A (bf16 always): 32 rows/wave, 8 chunks x 8 bf16 per row ----
#pragma unroll
    for (int t = 0; t < 4; t++) {
      int r = wave * 32 + t * 8 + (lane >> 3);
      int p = cL ^ (r & 7);  // physical chunk slot (xor swizzle)
      shortx8 va = *(const shortx8*)(A + (size_t)(m0 + r) * K + k0 + cL * 8);
      *(shortx8*)(As + r * 64 + p * 8) = va;
    }
    // ---- stage B ----
    if (!bfp32) {
      const unsigned short* B16 = (const unsigned short*)B;
#pragma unroll
      for (int t = 0; t < 4; t++) {
        int r = wave * 32 + t * 8 + (lane >> 3);
        int p = cL ^ (r & 7);
        shortx8 vb = *(const shortx8*)(B16 + (size_t)(n0 + r) * K + k0 + cL * 8);
        *(shortx8*)(Bs + r * 64 + p * 8) = vb;
      }
    } else {
      const float* Bf = (const float*)B;
#pragma unroll
      for (int t = 0; t < 4; t++) {
        int r = wave * 32 + t * 8 + (lane >> 3);
        int p = cL ^ (r & 7);
        const float4* src = (const float4*)(Bf + (size_t)(n0 + r) * K + k0 + cL * 8);
        float4 f0 = src[0], f1 = src[1];
        shortx8 vb;
        vb[0] = (short)f2bf(f0.x); vb[1] = (short)f2bf(f0.y);
        vb[2] = (short)f2bf(f0.z); vb[3] = (short)f2bf(f0.w);
        vb[4] = (short)f2bf(f1.x); vb[5] = (short)f2bf(f1.y);
        vb[6] = (short)f2bf(f1.z); vb[7] = (short)f2bf(f1.w);
        *(shortx8*)(Bs + r * 64 + p * 8) = vb;
      }
    }
    __syncthreads();
    // ---- MFMA over the 64-wide K tile ----
#pragma unroll
    for (int ks = 0; ks < 2; ks++) {
      shortx8 af[4], bfr[4];
#pragma unroll
      for (int mt = 0; mt < 4; mt++) {
        int r = wr * 64 + mt * 16 + l15;
        int ch = (ks * 4 + quad) ^ (r & 7);
        af[mt] = *(const shortx8*)(As + r * 64 + ch * 8);
      }
#pragma unroll
      for (int nt = 0; nt < 4; nt++) {
        int r = wc * 64 + nt * 16 + l15;
        int ch = (ks * 4 + quad) ^ (r & 7);
        bfr[nt] = *(const shortx8*)(Bs + r * 64 + ch * 8);
      }
#pragma unroll
      for (int mt = 0; mt < 4; mt++)
#pragma unroll
        for (int nt = 0; nt < 4; nt++)
          acc[mt][nt] = __builtin_amdgcn_mfma_f32_16x16x32_bf16(
              af[mt], bfr[nt], acc[mt][nt], 0, 0, 0);
    }
    __syncthreads();
  }

  // Epilogue. C/D layout (m91-verified): col = lane&15, row = (lane>>4)*4 + reg.
  const int lrow = quad * 4;
  if constexpr (EPI == 0) {
    float* Cf = (float*)Cout;
#pragma unroll
    for (int mt = 0; mt < 4; mt++)
#pragma unroll
      for (int nt = 0; nt < 4; nt++) {
        int gm = m0 + wr * 64 + mt * 16 + lrow;
        int gn = n0 + wc * 64 + nt * 16 + l15;
        float bz = lde(biasp, gn, fl);
#pragma unroll
        for (int r = 0; r < 4; r++)
          Cf[(size_t)(gm + r) * N + gn] = acc[mt][nt][r] + bz;
      }
  } else if constexpr (EPI == 1) {
    unsigned short* Cb = (unsigned short*)Cout;
#pragma unroll
    for (int mt = 0; mt < 4; mt++)
#pragma unroll
      for (int nt = 0; nt < 4; nt++) {
        int gm = m0 + wr * 64 + mt * 16 + lrow;
        int gn = n0 + wc * 64 + nt * 16 + l15;
#pragma unroll
        for (int r = 0; r < 4; r++)
          Cb[(size_t)(gm + r) * N + gn] = f2bf(acc[mt][nt][r]);
      }
  } else {
    const float* cp = (const float*)biasp;
    float w2v[4];
#pragma unroll
    for (int j = 0; j < 4; j++) w2v[j] = lde(W2b, j, fl);
    float b2v = lde(b2b, 0, fl);
#pragma unroll
    for (int mt = 0; mt < 4; mt++) {
      int gm = m0 + wr * 64 + mt * 16 + lrow;  // multiple of 4: rows gm..gm+3 = j 0..3
      float cpv0 = cp[gm], cpv1 = cp[gm + 1], cpv2 = cp[gm + 2], cpv3 = cp[gm + 3];
#pragma unroll
      for (int nt = 0; nt < 4; nt++) {
        int gn = n0 + wc * 64 + nt * 16 + l15;
        floatx4 v = acc[mt][nt];
        float s = b2v;
        s += w2v[0] * geluf(v[0] + cpv0);
        s += w2v[1] * geluf(v[1] + cpv1);
        s += w2v[2] * geluf(v[2] + cpv2);
        s += w2v[3] * geluf(v[3] + cpv3);
        size_t oi = (size_t)(gm >> 2) * N + gn;
        if (fl) ((float*)Cout)[oi] = s;
        else    ((unsigned short*)Cout)[oi] = f2bf(s);
      }
    }
  }
}

// QW[(b*4+j), e] = SCALE * W1[j][e/96] * q[b,e]  (bf16 out; q is fp32 ws)
// cp[b*4+j]      = b1[j] + SCALE * sum_h W1[j,h] * dot(q[b,h*96:],bk[h*96:])
__global__ void build_qw(const float* __restrict__ q,
                         const void* __restrict__ W1,
                         const void* __restrict__ b1,
                         const void* __restrict__ bk,
                         unsigned short* __restrict__ QW,
                         float* __restrict__ cp,
                         const int* __restrict__ flagp) {
  int fl = *flagp;
  int b = blockIdx.x, t = threadIdx.x;
  __shared__ float red[768];
  __shared__ float w1s[32];
  __shared__ float hcs[8];
  if (t < 32) w1s[t] = lde(W1, t, fl);
  __syncthreads();
  const float* qrow = q + b * 768;
  for (int e = t; e < 768; e += 256) {
    float qv = qrow[e];
    red[e] = qv * lde(bk, e, fl);
    int h = e / 96;
#pragma unroll
    for (int j = 0; j < 4; j++)
      QW[(size_t)(b * 4 + j) * 768 + e] = f2bf(qv * w1s[j * 8 + h] * SCALE);
  }
  __syncthreads();
  if (t < 8) {
    float s = 0.f;
    for (int d = 0; d < 96; d++) s += red[t * 96 + d];
    hcs[t] = s;
  }
  __syncthreads();
  if (t < 4) {
    float s = lde(b1, t, fl);
#pragma unroll
    for (int h = 0; h < 8; h++) s += SCALE * w1s[t * 8 + h] * hcs[h];
    cp[b * 4 + t] = s;
  }
}

extern "C" void kernel_launch(void* const* d_in, const int* in_sizes, int n_in,
                              void* d_out, int out_size, void* d_ws, size_t ws_size,
                              hipStream_t stream) {
  const void* query  = d_in[0];  // 256x768
  const void* search = d_in[1];  // 16384x768
  const void* Wq     = d_in[2];  // 768x768
  const void* bq     = d_in[3];  // 768
  const void* Wk     = d_in[4];  // 768x768
  const void* bk     = d_in[5];  // 768
  const void* W1     = d_in[6];  // 4x8
  const void* b1     = d_in[7];  // 4
  const void* W2     = d_in[8];  // 4
  const void* b2     = d_in[9];  // 1

  char* ws = (char*)d_ws;
  int*            flag = (int*)ws;                              // 16 B
  unsigned short* qb   = (unsigned short*)(ws + 16);            // 393,216 B
  unsigned short* wqb  = (unsigned short*)(ws + 393232);        // 1,179,648 B
  unsigned short* WkT  = (unsigned short*)(ws + 1572880);       // 1,179,648 B
  float*          qf   = (float*)(ws + 2752528);                //   786,432 B
  unsigned short* QW   = (unsigned short*)(ws + 3538960);       // 1,572,864 B
  unsigned short* QQ   = (unsigned short*)(ws + 5111824);       // 1,572,864 B
  float*          cp   = (float*)(ws + 6684688);                //     4,096 B

  // 0) dtype flag from `search`
  detect_dtype<<<1, 64, 0, stream>>>((const unsigned short*)search, flag);
  // 1) canonical bf16 copies of query, Wq
  convert_in<<<3072, 256, 0, stream>>>(query, Wq, qb, wqb, flag);
  // 2) Wk -> WkT (bf16)
  transpose_bf<<<dim3(24, 24), dim3(32, 8), 0, stream>>>(Wk, WkT, flag);
  // 3) qf = query @ Wq^T + bq   (fp32 out)
  gemm_bt<0><<<dim3(6, 2), 256, 0, stream>>>(qb, wqb, qf, bq, nullptr, nullptr,
                                             flag, 0, 256, 768, 768);
  // 4) QW, cp
  build_qw<<<256, 256, 0, stream>>>(qf, W1, b1, bk, QW, cp, flag);
  // 5) QQ = QW @ WkT^T = QW @ Wk   (bf16 out)
  gemm_bt<1><<<dim3(6, 8), 256, 0, stream>>>(QW, WkT, QQ, nullptr, nullptr, nullptr,
                                             flag, 0, 1024, 768, 768);
  // 6) main: out = MLP-epilogue( QQ @ search^T + cp ), B staged per flag
  gemm_bt<2><<<dim3(128, 8), 256, 0, stream>>>(QQ, search, d_out, cp, W2, b2,
                                               flag, 1, 1024, 16384, 768);
}

// Round 3
// 180.999 us; speedup vs baseline: 1.1320x; 1.1320x over previous
//
#include <hip/hip_runtime.h>
#include <math.h>

#define SCALE 0.1020620726159658f  // 96^-0.5

typedef __attribute__((ext_vector_type(8))) short shortx8;
typedef __attribute__((ext_vector_type(4))) float floatx4;

__device__ __forceinline__ float bf2f(unsigned short u) {
  union { unsigned int i; float f; } c; c.i = ((unsigned int)u) << 16; return c.f;
}
__device__ __forceinline__ unsigned short f2bf(float f) {
  union { float f; unsigned int i; } c; c.f = f;
  unsigned int x = c.i;
  x += 0x7fffu + ((x >> 16) & 1u);
  return (unsigned short)(x >> 16);
}
// tanh-form gelu via native exp2; |err vs erf-gelu| <~1e-3, well inside threshold
__device__ __forceinline__ float gelu_fast(float x) {
  float x2 = x * x;
  float y = x * (0.7978845608f + 0.0356774081f * x2);
  float e = fminf(y * 2.885390082f, 60.0f);  // 2*log2(e)*y, capped (large x -> gelu=x)
  float t = exp2f(e);
  return x * t * __builtin_amdgcn_rcpf(t + 1.0f);
}
// async global->LDS, 16B/lane; LDS dest is wave-uniform base + lane*16
__device__ __forceinline__ void async_ld16(const unsigned short* g, unsigned short* l) {
  __builtin_amdgcn_global_load_lds(
      (const __attribute__((address_space(1))) unsigned int*)g,
      (__attribute__((address_space(3))) unsigned int*)l, 16, 0, 0);
}

// C = A @ B^T. A: MxK bf16 row-major. B: NxK bf16 (bconv=0, async-staged) or
// fp32 (bconv=1, convert during ds_write staging — fallback only).
// 128x128 tile, BK=64, 256 thr / 4 waves, XOR chunk swizzle (0 LDS conflicts).
// EPI 0: q-proj epilogue -> writes QW (bf16, (4M)xN) and qf (fp32 MxN)
// EPI 1: plain bf16 store
// EPI 2: fused MLP epilogue -> fp32 out[(gm>>2), gn]
template <int EPI>
__global__ __launch_bounds__(256) void gemm_bt(
    const unsigned short* __restrict__ A,
    const void* __restrict__ B,
    void* __restrict__ Cout,
    const void* __restrict__ p0, const void* __restrict__ p1,
    void* __restrict__ p2, const void* __restrict__ p3,
    int bconv, int M, int N, int K)
{
  __shared__ unsigned short As[128 * 64];
  __shared__ unsigned short Bs[128 * 64];
  const int tid = threadIdx.x;
  const int wave = tid >> 6;
  const int lane = tid & 63;
  const int wr = wave >> 1, wc = wave & 1;
  const int m0 = blockIdx.y * 128;
  const int n0 = blockIdx.x * 128;

  floatx4 acc[4][4];
#pragma unroll
  for (int i = 0; i < 4; i++)
#pragma unroll
    for (int j = 0; j < 4; j++) acc[i][j] = (floatx4){0.f, 0.f, 0.f, 0.f};

  // Async staging: per instr t, wave covers rows wave*32+t*8+(lane>>3),
  // lane fetches global chunk (lane&7)^(lane>>3) -> LDS slot (lane&7) (xor swizzle).
  const int rl = lane >> 3;        // row-within-group 0..7 (== r&7)
  const int cl = (lane & 7) ^ rl;  // swizzled global chunk
  const unsigned short* gA[4];
  const unsigned short* gB[4];
  unsigned short* lA[4];
  unsigned short* lB[4];
#pragma unroll
  for (int t = 0; t < 4; t++) {
    int r = wave * 32 + t * 8 + rl;
    gA[t] = A + (size_t)(m0 + r) * K + cl * 8;
    gB[t] = (const unsigned short*)B + (size_t)(n0 + r) * K + cl * 8;
    lA[t] = As + (wave * 32 + t * 8) * 64;
    lB[t] = Bs + (wave * 32 + t * 8) * 64;
  }
  const int cL = lane & 7;
  const int quad = lane >> 4;
  const int l15 = lane & 15;

  for (int k0 = 0; k0 < K; k0 += 64) {
#pragma unroll
    for (int t = 0; t < 4; t++) async_ld16(gA[t] + k0, lA[t]);
    if (!bconv) {
#pragma unroll
      for (int t = 0; t < 4; t++) async_ld16(gB[t] + k0, lB[t]);
    } else {
      const float* Bf = (const float*)B;
#pragma unroll
      for (int t = 0; t < 4; t++) {
        int r = wave * 32 + t * 8 + rl;
        int p = cL ^ rl;
        const float4* src = (const float4*)(Bf + (size_t)(n0 + r) * K + k0 + cL * 8);
        float4 f0 = src[0], f1 = src[1];
        shortx8 vb;
        vb[0] = (short)f2bf(f0.x); vb[1] = (short)f2bf(f0.y);
        vb[2] = (short)f2bf(f0.z); vb[3] = (short)f2bf(f0.w);
        vb[4] = (short)f2bf(f1.x); vb[5] = (short)f2bf(f1.y);
        vb[6] = (short)f2bf(f1.z); vb[7] = (short)f2bf(f1.w);
        *(shortx8*)(Bs + r * 64 + p * 8) = vb;
      }
    }
    __syncthreads();  // drains vmcnt+lgkmcnt, publishes LDS
#pragma unroll
    for (int ks = 0; ks < 2; ks++) {
      shortx8 af[4], bfr[4];
#pragma unroll
      for (int mt = 0; mt < 4; mt++) {
        int r = wr * 64 + mt * 16 + l15;
        int ch = (ks * 4 + quad) ^ (r & 7);
        af[mt] = *(const shortx8*)(As + r * 64 + ch * 8);
      }
#pragma unroll
      for (int nt = 0; nt < 4; nt++) {
        int r = wc * 64 + nt * 16 + l15;
        int ch = (ks * 4 + quad) ^ (r & 7);
        bfr[nt] = *(const shortx8*)(Bs + r * 64 + ch * 8);
      }
#pragma unroll
      for (int mt = 0; mt < 4; mt++)
#pragma unroll
        for (int nt = 0; nt < 4; nt++)
          acc[mt][nt] = __builtin_amdgcn_mfma_f32_16x16x32_bf16(
              af[mt], bfr[nt], acc[mt][nt], 0, 0, 0);
    }
    __syncthreads();
  }

  // Epilogue. C/D layout (m91-verified): col = lane&15, row = (lane>>4)*4 + reg.
  const int lrow = quad * 4;
  if constexpr (EPI == 0) {
    // q-proj: qv = C + bq[col]; QW[(row*4+j),col] = bf16(SCALE*W1[j,col/96]*qv);
    // qf[row,col] = qv (fp32, for the cp finisher)
    const float* bqv = (const float*)p0;
    const float* W1f = (const float*)p1;
    float* qf = (float*)p2;
    unsigned short* QWo = (unsigned short*)Cout;
#pragma unroll
    for (int mt = 0; mt < 4; mt++)
#pragma unroll
      for (int nt = 0; nt < 4; nt++) {
        int gm = m0 + wr * 64 + mt * 16 + lrow;
        int gn = n0 + wc * 64 + nt * 16 + l15;
        float bz = bqv[gn];
        int h = gn / 96;
        float w1h0 = W1f[h], w1h1 = W1f[8 + h], w1h2 = W1f[16 + h], w1h3 = W1f[24 + h];
#pragma unroll
        for (int r = 0; r < 4; r++) {
          float qv = acc[mt][nt][r] + bz;
          qf[(size_t)(gm + r) * N + gn] = qv;
          size_t base = (size_t)((gm + r) * 4) * N + gn;
          QWo[base]         = f2bf(SCALE * w1h0 * qv);
          QWo[base + N]     = f2bf(SCALE * w1h1 * qv);
          QWo[base + 2 * N] = f2bf(SCALE * w1h2 * qv);
          QWo[base + 3 * N] = f2bf(SCALE * w1h3 * qv);
        }
      }
  } else if constexpr (EPI == 1) {
    unsigned short* Cb = (unsigned short*)Cout;
#pragma unroll
    for (int mt = 0; mt < 4; mt++)
#pragma unroll
      for (int nt = 0; nt < 4; nt++) {
        int gm = m0 + wr * 64 + mt * 16 + lrow;
        int gn = n0 + wc * 64 + nt * 16 + l15;
#pragma unroll
        for (int r = 0; r < 4; r++)
          Cb[(size_t)(gm + r) * N + gn] = f2bf(acc[mt][nt][r]);
      }
  } else {
    const float* cp = (const float*)p0;
    const float* W2f = (const float*)p1;
    const float* b2f = (const float*)p3;
    float* Co = (float*)Cout;
    float w2v0 = W2f[0], w2v1 = W2f[1], w2v2 = W2f[2], w2v3 = W2f[3];
    float b2v = b2f[0];
#pragma unroll
    for (int mt = 0; mt < 4; mt++) {
      int gm = m0 + wr * 64 + mt * 16 + lrow;  // multiple of 4: rows gm..gm+3 = j 0..3
      float cpv0 = cp[gm], cpv1 = cp[gm + 1], cpv2 = cp[gm + 2], cpv3 = cp[gm + 3];
#pragma unroll
      for (int nt = 0; nt < 4; nt++) {
        int gn = n0 + wc * 64 + nt * 16 + l15;
        floatx4 v = acc[mt][nt];
        float s = b2v;
        s += w2v0 * gelu_fast(v[0] + cpv0);
        s += w2v1 * gelu_fast(v[1] + cpv1);
        s += w2v2 * gelu_fast(v[2] + cpv2);
        s += w2v3 * gelu_fast(v[3] + cpv3);
        Co[(size_t)(gm >> 2) * N + gn] = s;
      }
    }
  }
}

__device__ __forceinline__ void cvt8(const float* __restrict__ src,
                                     unsigned short* __restrict__ dst, size_t i) {
  float4 a = *(const float4*)(src + i);
  float4 b = *(const float4*)(src + i + 4);
  shortx8 v;
  v[0] = (short)f2bf(a.x); v[1] = (short)f2bf(a.y);
  v[2] = (short)f2bf(a.z); v[3] = (short)f2bf(a.w);
  v[4] = (short)f2bf(b.x); v[5] = (short)f2bf(b.y);
  v[6] = (short)f2bf(b.z); v[7] = (short)f2bf(b.w);
  *(shortx8*)(dst + i) = v;
}

// Fused prep: Wk transpose->bf16 (blocks 0..575), query->qb (576..671),
// Wq->wqb (672..959), search->sb (960.. , only if use_sb)
__global__ __launch_bounds__(256) void prep(
    const float* __restrict__ query, const float* __restrict__ Wq,
    const float* __restrict__ Wk, const float* __restrict__ search,
    unsigned short* __restrict__ qb, unsigned short* __restrict__ wqb,
    unsigned short* __restrict__ WkT, unsigned short* __restrict__ sb)
{
  int b = blockIdx.x, t = threadIdx.x;
  if (b < 576) {
    __shared__ unsigned short tile[32][33];
    int bx = b % 24, by = b / 24;
    int tx = t & 31, ty = t >> 5;
#pragma unroll
    for (int i = 0; i < 4; i++)
      tile[ty + i * 8][tx] = f2bf(Wk[(size_t)(by * 32 + ty + i * 8) * 768 + bx * 32 + tx]);
    __syncthreads();
#pragma unroll
    for (int i = 0; i < 4; i++)
      WkT[(size_t)(bx * 32 + ty + i * 8) * 768 + by * 32 + tx] = tile[tx][ty + i * 8];
  } else if (b < 672) {
    cvt8(query, qb, (size_t)(b - 576) * 2048 + t * 8);
  } else if (b < 960) {
    cvt8(Wq, wqb, (size_t)(b - 672) * 2048 + t * 8);
  } else {
    cvt8(search, sb, (size_t)(b - 960) * 2048 + t * 8);
  }
}

// cp[b*4+j] = b1[j] + SCALE * sum_h W1[j,h] * dot(qf[b, h*96:(h+1)*96], bk[...])
__global__ __launch_bounds__(256) void finish_cp(
    const float* __restrict__ qf, const float* __restrict__ W1f,
    const float* __restrict__ b1f, const float* __restrict__ bkf,
    float* __restrict__ cp)
{
  int b = blockIdx.x, t = threadIdx.x;
  __shared__ float red[768];
  __shared__ float hcs[8];
  const float* qrow = qf + (size_t)b * 768;
  for (int e = t; e < 768; e += 256) red[e] = qrow[e] * bkf[e];
  __syncthreads();
  if (t < 8) {
    float s = 0.f;
    for (int d = 0; d < 96; d++) s += red[t * 96 + d];
    hcs[t] = s;
  }
  __syncthreads();
  if (t < 4) {
    float s = b1f[t];
#pragma unroll
    for (int h = 0; h < 8; h++) s += SCALE * W1f[t * 8 + h] * hcs[h];
    cp[b * 4 + t] = s;
  }
}

extern "C" void kernel_launch(void* const* d_in, const int* in_sizes, int n_in,
                              void* d_out, int out_size, void* d_ws, size_t ws_size,
                              hipStream_t stream) {
  // fp32 world (confirmed round 2: FETCH 56 MB = fp32 search; fp32 out passed)
  const float* query  = (const float*)d_in[0];  // 256x768
  const float* search = (const float*)d_in[1];  // 16384x768
  const float* Wq     = (const float*)d_in[2];  // 768x768
  const float* bq     = (const float*)d_in[3];  // 768
  const float* Wk     = (const float*)d_in[4];  // 768x768
  const float* bk     = (const float*)d_in[5];  // 768
  const float* W1     = (const float*)d_in[6];  // 4x8
  const float* b1     = (const float*)d_in[7];  // 4
  const float* W2     = (const float*)d_in[8];  // 4
  const float* b2     = (const float*)d_in[9];  // 1

  char* ws = (char*)d_ws;
  float*          cp  = (float*)ws;                        //     4,096 B
  float*          qf  = (float*)(ws + 4096);               //   786,432 B
  unsigned short* qb  = (unsigned short*)(ws + 790528);    //   393,216 B
  unsigned short* wqb = (unsigned short*)(ws + 1183744);   // 1,179,648 B
  unsigned short* WkT = (unsigned short*)(ws + 2363392);   // 1,179,648 B
  unsigned short* QW  = (unsigned short*)(ws + 3543040);   // 1,572,864 B
  unsigned short* QQ  = (unsigned short*)(ws + 5115904);   // 1,572,864 B
  unsigned short* sb  = (unsigned short*)(ws + 6688768);   // 25,165,824 B
  const int use_sb = (ws_size >= 31854592) ? 1 : 0;

  // 1) converts + transpose (one fused kernel)
  prep<<<use_sb ? 7104 : 960, 256, 0, stream>>>(query, Wq, Wk, search, qb, wqb, WkT, sb);
  // 2) q-proj GEMM; epilogue writes QW (bf16 1024x768) + qf (fp32 256x768)
  gemm_bt<0><<<dim3(6, 2), 256, 0, stream>>>(qb, wqb, QW, bq, W1, qf, nullptr,
                                             0, 256, 768, 768);
  // 3) cp from qf
  finish_cp<<<256, 256, 0, stream>>>(qf, W1, b1, bk, cp);
  // 4) QQ = QW @ Wk  (bf16)
  gemm_bt<1><<<dim3(6, 8), 256, 0, stream>>>(QW, WkT, QQ, nullptr, nullptr, nullptr,
                                             nullptr, 0, 1024, 768, 768);
  // 5) main: out = MLP-epilogue( QQ @ search^T + cp )
  if (use_sb)
    gemm_bt<2><<<dim3(128, 8), 256, 0, stream>>>(QQ, sb, d_out, cp, W2, nullptr,
                                                 (void*)b2, 0, 1024, 16384, 768);
  else
    gemm_bt<2><<<dim3(128, 8), 256, 0, stream>>>(QQ, search, d_out, cp, W2, nullptr,
                                                 (void*)b2, 1, 1024, 16384, 768);
}

// Round 4
// 180.661 us; speedup vs baseline: 1.1341x; 1.0019x over previous
//
#include <hip/hip_runtime.h>
#include <math.h>

#define SCALE 0.1020620726159658f  // 96^-0.5

typedef __attribute__((ext_vector_type(8))) short shortx8;
typedef __attribute__((ext_vector_type(4))) float floatx4;

__device__ __forceinline__ float bf2f(unsigned short u) {
  union { unsigned int i; float f; } c; c.i = ((unsigned int)u) << 16; return c.f;
}
__device__ __forceinline__ unsigned short f2bf(float f) {
  union { float f; unsigned int i; } c; c.f = f;
  unsigned int x = c.i;
  x += 0x7fffu + ((x >> 16) & 1u);
  return (unsigned short)(x >> 16);
}
// tanh-form gelu via native exp2 (validated round 3: absmax 0.0039)
__device__ __forceinline__ float gelu_fast(float x) {
  float x2 = x * x;
  float y = x * (0.7978845608f + 0.0356774081f * x2);
  float e = fminf(y * 2.885390082f, 60.0f);
  float t = exp2f(e);
  return x * t * __builtin_amdgcn_rcpf(t + 1.0f);
}
__device__ __forceinline__ void async_ld16(const unsigned short* g, unsigned short* l) {
  __builtin_amdgcn_global_load_lds(
      (const __attribute__((address_space(1))) unsigned int*)g,
      (__attribute__((address_space(3))) unsigned int*)l, 16, 0, 0);
}
__device__ __forceinline__ void cvt8(const float* __restrict__ src,
                                     unsigned short* __restrict__ dst, size_t i) {
  float4 a = *(const float4*)(src + i);
  float4 b = *(const float4*)(src + i + 4);
  shortx8 v;
  v[0] = (short)f2bf(a.x); v[1] = (short)f2bf(a.y);
  v[2] = (short)f2bf(a.z); v[3] = (short)f2bf(a.w);
  v[4] = (short)f2bf(b.x); v[5] = (short)f2bf(b.y);
  v[6] = (short)f2bf(b.z); v[7] = (short)f2bf(b.w);
  *(shortx8*)(dst + i) = v;
}
// fp32 global -> bf16 LDS staging (ds_write path), XOR chunk swizzle
__device__ __forceinline__ void stage_f32(const float* __restrict__ src, int ldk,
                                          unsigned short* __restrict__ lds,
                                          int wave, int lane, int row0, int k0) {
  int rl = lane >> 3, cL = lane & 7;
#pragma unroll
  for (int t = 0; t < 4; t++) {
    int r = wave * 32 + t * 8 + rl;
    int p = cL ^ rl;
    const float4* s4 = (const float4*)(src + (size_t)(row0 + r) * ldk + k0 + cL * 8);
    float4 f0 = s4[0], f1 = s4[1];
    shortx8 v;
    v[0] = (short)f2bf(f0.x); v[1] = (short)f2bf(f0.y);
    v[2] = (short)f2bf(f0.z); v[3] = (short)f2bf(f0.w);
    v[4] = (short)f2bf(f1.x); v[5] = (short)f2bf(f1.y);
    v[6] = (short)f2bf(f1.z); v[7] = (short)f2bf(f1.w);
    *(shortx8*)(lds + r * 64 + p * 8) = v;
  }
}
// MFMA consume of one 128x128x64 LDS tile (16x16x32 bf16, 4 waves, 64x64/wave)
__device__ __forceinline__ void mfma_consume(const unsigned short* __restrict__ As,
                                             const unsigned short* __restrict__ Bs,
                                             int wr, int wc, int quad, int l15,
                                             floatx4 (&acc)[4][4]) {
#pragma unroll
  for (int ks = 0; ks < 2; ks++) {
    shortx8 af[4], bfr[4];
#pragma unroll
    for (int mt = 0; mt < 4; mt++) {
      int r = wr * 64 + mt * 16 + l15;
      int ch = (ks * 4 + quad) ^ (r & 7);
      af[mt] = *(const shortx8*)(As + r * 64 + ch * 8);
    }
#pragma unroll
    for (int nt = 0; nt < 4; nt++) {
      int r = wc * 64 + nt * 16 + l15;
      int ch = (ks * 4 + quad) ^ (r & 7);
      bfr[nt] = *(const shortx8*)(Bs + r * 64 + ch * 8);
    }
#pragma unroll
    for (int mt = 0; mt < 4; mt++)
#pragma unroll
      for (int nt = 0; nt < 4; nt++)
        acc[mt][nt] = __builtin_amdgcn_mfma_f32_16x16x32_bf16(
            af[mt], bfr[nt], acc[mt][nt], 0, 0, 0);
  }
}

// Launch 1: blocks [0,12) q-proj GEMM (fp32-staged); [12,588) Wk transpose;
// [588, 588+6144) search fp32->bf16 convert (only when use_sb).
__global__ __launch_bounds__(256) void fused_pre(
    const float* __restrict__ query, const float* __restrict__ Wq,
    const float* __restrict__ Wk, const float* __restrict__ search,
    const float* __restrict__ bq, const float* __restrict__ W1,
    unsigned short* __restrict__ WkT, unsigned short* __restrict__ QW,
    float* __restrict__ qf, unsigned short* __restrict__ sb)
{
  const int bid = blockIdx.x, t = threadIdx.x;
  if (bid < 12) {
    // qf/QW: C = query @ Wq^T + bq; M=256, N=768, K=768
    __shared__ unsigned short As[128 * 64];
    __shared__ unsigned short Bs[128 * 64];
    const int bx = bid % 6, by = bid / 6;
    const int m0 = by * 128, n0 = bx * 128;
    const int wave = t >> 6, lane = t & 63;
    const int wr = wave >> 1, wc = wave & 1;
    const int quad = lane >> 4, l15 = lane & 15;
    floatx4 acc[4][4];
#pragma unroll
    for (int i = 0; i < 4; i++)
#pragma unroll
      for (int j = 0; j < 4; j++) acc[i][j] = (floatx4){0.f, 0.f, 0.f, 0.f};
    for (int k0 = 0; k0 < 768; k0 += 64) {
      stage_f32(query, 768, As, wave, lane, m0, k0);
      stage_f32(Wq, 768, Bs, wave, lane, n0, k0);
      __syncthreads();
      mfma_consume(As, Bs, wr, wc, quad, l15, acc);
      __syncthreads();
    }
    // EPI0: qv = C + bq[col]; qf fp32; QW[(row*4+j),col] = bf16(SCALE*W1[j,h]*qv)
    const int N = 768;
    const int lrow = quad * 4;
#pragma unroll
    for (int mt = 0; mt < 4; mt++)
#pragma unroll
      for (int nt = 0; nt < 4; nt++) {
        int gm = m0 + wr * 64 + mt * 16 + lrow;
        int gn = n0 + wc * 64 + nt * 16 + l15;
        float bz = bq[gn];
        int h = gn / 96;
        float w1h0 = W1[h], w1h1 = W1[8 + h], w1h2 = W1[16 + h], w1h3 = W1[24 + h];
#pragma unroll
        for (int r = 0; r < 4; r++) {
          float qv = acc[mt][nt][r] + bz;
          qf[(size_t)(gm + r) * N + gn] = qv;
          size_t base = (size_t)((gm + r) * 4) * N + gn;
          QW[base]         = f2bf(SCALE * w1h0 * qv);
          QW[base + N]     = f2bf(SCALE * w1h1 * qv);
          QW[base + 2 * N] = f2bf(SCALE * w1h2 * qv);
          QW[base + 3 * N] = f2bf(SCALE * w1h3 * qv);
        }
      }
  } else if (bid < 588) {
    __shared__ unsigned short tile[32][33];
    const int tb = bid - 12, bx = tb % 24, by = tb / 24;
    const int tx = t & 31, ty = t >> 5;
#pragma unroll
    for (int i = 0; i < 4; i++)
      tile[ty + i * 8][tx] = f2bf(Wk[(size_t)(by * 32 + ty + i * 8) * 768 + bx * 32 + tx]);
    __syncthreads();
#pragma unroll
    for (int i = 0; i < 4; i++)
      WkT[(size_t)(bx * 32 + ty + i * 8) * 768 + by * 32 + tx] = tile[tx][ty + i * 8];
  } else {
    cvt8(search, sb, (size_t)(bid - 588) * 2048 + t * 8);
  }
}

// Launch 2: y<8 -> QQ = QW @ WkT^T (bf16, async-staged); y==8 -> cp finisher.
__global__ __launch_bounds__(256) void mid(
    const unsigned short* __restrict__ QW, const unsigned short* __restrict__ WkT,
    unsigned short* __restrict__ QQ,
    const float* __restrict__ qf, const float* __restrict__ W1,
    const float* __restrict__ b1, const float* __restrict__ bk,
    float* __restrict__ cp)
{
  const int t = threadIdx.x;
  const int wave = t >> 6, lane = t & 63;
  if (blockIdx.y < 8) {
    __shared__ unsigned short As[128 * 64];
    __shared__ unsigned short Bs[128 * 64];
    const int m0 = blockIdx.y * 128, n0 = blockIdx.x * 128;
    const int K = 768, N = 768;
    const int wr = wave >> 1, wc = wave & 1;
    const int quad = lane >> 4, l15 = lane & 15;
    floatx4 acc[4][4];
#pragma unroll
    for (int i = 0; i < 4; i++)
#pragma unroll
      for (int j = 0; j < 4; j++) acc[i][j] = (floatx4){0.f, 0.f, 0.f, 0.f};
    const int rl = lane >> 3, cl = (lane & 7) ^ rl;
    const unsigned short* gA[4];
    const unsigned short* gB[4];
    unsigned short* lA[4];
    unsigned short* lB[4];
#pragma unroll
    for (int tt = 0; tt < 4; tt++) {
      int r = wave * 32 + tt * 8 + rl;
      gA[tt] = QW + (size_t)(m0 + r) * K + cl * 8;
      gB[tt] = WkT + (size_t)(n0 + r) * K + cl * 8;
      lA[tt] = As + (wave * 32 + tt * 8) * 64;
      lB[tt] = Bs + (wave * 32 + tt * 8) * 64;
    }
    for (int k0 = 0; k0 < K; k0 += 64) {
#pragma unroll
      for (int tt = 0; tt < 4; tt++) async_ld16(gA[tt] + k0, lA[tt]);
#pragma unroll
      for (int tt = 0; tt < 4; tt++) async_ld16(gB[tt] + k0, lB[tt]);
      __syncthreads();
      mfma_consume(As, Bs, wr, wc, quad, l15, acc);
      __syncthreads();
    }
    const int lrow = quad * 4;
#pragma unroll
    for (int mt = 0; mt < 4; mt++)
#pragma unroll
      for (int nt = 0; nt < 4; nt++) {
        int gm = m0 + wr * 64 + mt * 16 + lrow;
        int gn = n0 + wc * 64 + nt * 16 + l15;
#pragma unroll
        for (int r = 0; r < 4; r++)
          QQ[(size_t)(gm + r) * N + gn] = f2bf(acc[mt][nt][r]);
      }
  } else {
    // cp[b*4+j] = b1[j] + SCALE * sum_h W1[j,h] * dot(qf[b,h*96:],bk[h*96:])
    const int bstart = blockIdx.x * 43;
    const int bend = min(bstart + 43, 256);
    for (int b = bstart + wave; b < bend; b += 4) {
      const float* qrow = qf + (size_t)b * 768;
      int e0 = lane * 12;  // 12 elems/lane, head = lane>>3 (96 = 8 lanes * 12)
      float s = 0.f;
#pragma unroll
      for (int i = 0; i < 12; i++) s += qrow[e0 + i] * bk[e0 + i];
      s += __shfl_xor(s, 1); s += __shfl_xor(s, 2); s += __shfl_xor(s, 4);
      float v = __shfl(s, (lane & 7) * 8);          // v = hs[lane&7]
      float w = W1[((lane >> 3) & 3) * 8 + (lane & 7)] * v;  // j = lane>>3 (<4 valid)
      w += __shfl_xor(w, 1); w += __shfl_xor(w, 2); w += __shfl_xor(w, 4);
      if (lane < 32 && (lane & 7) == 0) {
        int j = lane >> 3;
        cp[b * 4 + j] = b1[j] + SCALE * w;
      }
    }
  }
}

// Launch 3: out = MLP-epilogue( QQ @ B^T + cp ); B bf16 async (bconv=0) or
// fp32 ds_write fallback. XCD swizzle: bid%8 -> contiguous 16-n-tile range.
__global__ __launch_bounds__(256) void gemm_main(
    const unsigned short* __restrict__ QQ, const void* __restrict__ Bv,
    float* __restrict__ out, const float* __restrict__ cp,
    const float* __restrict__ W2, const float* __restrict__ b2, int bconv)
{
  __shared__ unsigned short As[128 * 64];
  __shared__ unsigned short Bs[128 * 64];
  const int bid = blockIdx.x;
  const int n_tile = (bid & 7) * 16 + ((bid >> 3) & 15);
  const int m_tile = bid >> 7;
  const int m0 = m_tile * 128, n0 = n_tile * 128;
  const int K = 768, N = 16384;
  const int t = threadIdx.x;
  const int wave = t >> 6, lane = t & 63;
  const int wr = wave >> 1, wc = wave & 1;
  const int quad = lane >> 4, l15 = lane & 15;
  floatx4 acc[4][4];
#pragma unroll
  for (int i = 0; i < 4; i++)
#pragma unroll
    for (int j = 0; j < 4; j++) acc[i][j] = (floatx4){0.f, 0.f, 0.f, 0.f};
  const int rl = lane >> 3, cl = (lane & 7) ^ rl;
  const unsigned short* gA[4];
  const unsigned short* gB[4];
  unsigned short* lA[4];
  unsigned short* lB[4];
#pragma unroll
  for (int tt = 0; tt < 4; tt++) {
    int r = wave * 32 + tt * 8 + rl;
    gA[tt] = QQ + (size_t)(m0 + r) * K + cl * 8;
    gB[tt] = (const unsigned short*)Bv + (size_t)(n0 + r) * K + cl * 8;
    lA[tt] = As + (wave * 32 + tt * 8) * 64;
    lB[tt] = Bs + (wave * 32 + tt * 8) * 64;
  }
  for (int k0 = 0; k0 < K; k0 += 64) {
#pragma unroll
    for (int tt = 0; tt < 4; tt++) async_ld16(gA[tt] + k0, lA[tt]);
    if (!bconv) {
#pragma unroll
      for (int tt = 0; tt < 4; tt++) async_ld16(gB[tt] + k0, lB[tt]);
    } else {
      stage_f32((const float*)Bv, K, Bs, wave, lane, n0, k0);
    }
    __syncthreads();
    mfma_consume(As, Bs, wr, wc, quad, l15, acc);
    __syncthreads();
  }
  // EPI2: rows gm = b*4+j; out[b,n] = b2 + sum_j W2[j]*gelu(C+cp)
  const float w2v0 = W2[0], w2v1 = W2[1], w2v2 = W2[2], w2v3 = W2[3];
  const float b2v = b2[0];
  const int lrow = quad * 4;
#pragma unroll
  for (int mt = 0; mt < 4; mt++) {
    int gm = m0 + wr * 64 + mt * 16 + lrow;  // multiple of 4
    float cpv0 = cp[gm], cpv1 = cp[gm + 1], cpv2 = cp[gm + 2], cpv3 = cp[gm + 3];
#pragma unroll
    for (int nt = 0; nt < 4; nt++) {
      int gn = n0 + wc * 64 + nt * 16 + l15;
      floatx4 v = acc[mt][nt];
      float s = b2v;
      s += w2v0 * gelu_fast(v[0] + cpv0);
      s += w2v1 * gelu_fast(v[1] + cpv1);
      s += w2v2 * gelu_fast(v[2] + cpv2);
      s += w2v3 * gelu_fast(v[3] + cpv3);
      out[(size_t)(gm >> 2) * N + gn] = s;
    }
  }
}

extern "C" void kernel_launch(void* const* d_in, const int* in_sizes, int n_in,
                              void* d_out, int out_size, void* d_ws, size_t ws_size,
                              hipStream_t stream) {
  const float* query  = (const float*)d_in[0];
  const float* search = (const float*)d_in[1];
  const float* Wq     = (const float*)d_in[2];
  const float* bq     = (const float*)d_in[3];
  const float* Wk     = (const float*)d_in[4];
  const float* bk     = (const float*)d_in[5];
  const float* W1     = (const float*)d_in[6];
  const float* b1     = (const float*)d_in[7];
  const float* W2     = (const float*)d_in[8];
  const float* b2     = (const float*)d_in[9];

  char* ws = (char*)d_ws;
  float*          cp  = (float*)ws;                       //     4,096 B
  float*          qf  = (float*)(ws + 4096);              //   786,432 B
  unsigned short* WkT = (unsigned short*)(ws + 790528);   // 1,179,648 B
  unsigned short* QW  = (unsigned short*)(ws + 1970176);  // 1,572,864 B
  unsigned short* QQ  = (unsigned short*)(ws + 3543040);  // 1,572,864 B
  unsigned short* sb  = (unsigned short*)(ws + 5115904);  // 25,165,824 B -> 30,281,728
  const int use_sb = (ws_size >= 30281728u) ? 1 : 0;

  // L1: search convert ∥ Wk transpose ∥ q-proj GEMM (+QW/qf epilogue)
  fused_pre<<<use_sb ? 6732 : 588, 256, 0, stream>>>(query, Wq, Wk, search,
                                                     bq, W1, WkT, QW, qf, sb);
  // L2: QQ GEMM + cp finisher
  mid<<<dim3(6, 9), 256, 0, stream>>>(QW, WkT, QQ, qf, W1, b1, bk, cp);
  // L3: main GEMM with fused MLP epilogue
  gemm_main<<<1024, 256, 0, stream>>>(QQ, use_sb ? (const void*)sb : (const void*)search,
                                      (float*)d_out, cp, W2, b2, use_sb ? 0 : 1);
}